// Round 1
// baseline (436.591 us; speedup 1.0000x reference)
//
#include <hip/hip_runtime.h>
#include <hip/hip_bf16.h>
#include <stdint.h>

typedef __bf16 bf16x8 __attribute__((ext_vector_type(8)));
typedef float  f32x4  __attribute__((ext_vector_type(4)));

#define NSLOPE 0.01f

// problem dims
#define NB   32
#define CIN  128
#define HIN  130
#define WIN  130
#define KOUT 256
#define POUT 128
#define QOUT 128
#define HWIN (HIN*WIN)            // 16900

// workspace layout: X' (NHWC bf16) then W' ([cc][r][s][k][ci] bf16)
#define XP_BYTES 138444800ull     // 32*130*130*128*2
#define WP_ELEMS (2*3*3*KOUT*64)  // 294912

__device__ __forceinline__ unsigned short f2bf(float f) {
    unsigned u = __builtin_bit_cast(unsigned, f);
    u += 0x7FFFu + ((u >> 16) & 1u);   // RNE
    return (unsigned short)(u >> 16);
}

__device__ __forceinline__ void g2lds16(const void* g, void* l) {
    __builtin_amdgcn_global_load_lds(
        (const __attribute__((address_space(1))) void*)g,
        (__attribute__((address_space(3))) void*)l,
        16, 0, 0);
}

// ---------------- pre-pass 1: X NCHW fp32 -> NHWC bf16 ----------------
// block = one (n,h) row: reads coalesced along w, LDS transpose, contiguous out
__global__ __launch_bounds__(256) void k_conv_x(const float* __restrict__ X,
                                                unsigned short* __restrict__ Xp) {
    __shared__ unsigned short tile[130*132];   // [w][c], c padded 128->132
    const int b = blockIdx.x;                  // n*130 + h
    const int n = b / 130, h = b - n*130;
    const int tid = threadIdx.x;
    const size_t in_base = (size_t)n*(CIN*(size_t)HWIN) + (size_t)h*WIN;
    for (int fi = tid; fi < CIN*WIN; fi += 256) {        // 16640 elems, 65 iters
        int c = fi / WIN, w = fi - c*WIN;
        tile[w*132 + c] = f2bf(X[in_base + (size_t)c*HWIN + w]);
    }
    __syncthreads();
    unsigned short* outp = Xp + (size_t)b * (WIN*CIN);
    for (int oi = tid; oi < (WIN*CIN)/4; oi += 256) {    // 4160 ushort4 chunks
        int e = oi*4; int w = e >> 7; int c4 = e & 127;  // 4 consecutive c, same w
        const unsigned short* t = &tile[w*132 + c4];
        ushort4 v; v.x = t[0]; v.y = t[1]; v.z = t[2]; v.w = t[3];
        *(ushort4*)(outp + e) = v;
    }
}

// ---------------- pre-pass 2: W OIHW fp32 -> [cc][r][s][k][ci] bf16 ----------------
__global__ __launch_bounds__(256) void k_conv_w(const float* __restrict__ W,
                                                unsigned short* __restrict__ Wp) {
    int e = blockIdx.x*256 + threadIdx.x;
    if (e >= WP_ELEMS) return;
    int ci = e & 63;
    int k  = (e >> 6) & 255;
    int rsIdx = e >> 14;                       // 0..17 = cc*9 + r*3 + s
    int cc = rsIdx / 9; int rem = rsIdx - cc*9; int r = rem / 3, s = rem - r*3;
    int c = cc*64 + ci;
    Wp[e] = f2bf(W[(size_t)k*1152 + (size_t)c*9 + r*3 + s]);
}

// ---------------- main conv: implicit GEMM, bf16 MFMA 16x16x32 ----------------
// block: 128 k_out x 128 q (one (n,p,kh)); 4 waves 2x2, 64x64 each.
// LDS: Xs [130 w][64 ci] @0 (16640 B) + Ws [3 s][128 kk][64 ci] @16640 (49152 B)
// both XOR-swizzled: phys = logical ^ ((logical>>3)&0x70)  (involution, bits 4-6 ^ row&7)
#define LDS_WS_OFF 16640
#define LDS_TOTAL  (16640 + 49152)             // 65792 B -> 2 blocks/CU (160 KiB LDS)

__global__ __launch_bounds__(256, 2) void k_conv_main(
    const unsigned short* __restrict__ Xp,
    const unsigned short* __restrict__ Wp,
    const float* __restrict__ bias,
    float* __restrict__ out)
{
    __shared__ __align__(16) unsigned char smem[LDS_TOTAL];

    const int tid  = threadIdx.x;
    const int lane = tid & 63;
    const int wid  = tid >> 6;
    const int wm   = wid >> 1;         // k_out 64-block within tile
    const int wn   = wid & 1;          // q 64-block within tile
    const int l15  = lane & 15;
    const int kg   = lane >> 4;        // 0..3

    // bijective XCD swizzle (8192 blocks, 8 XCDs -> contiguous 1024-chunks)
    const int L  = ((blockIdx.x & 7) << 10) | (blockIdx.x >> 3);
    const int kh = L & 1;
    const int np = L >> 1;
    const int p  = np & 127;
    const int n  = np >> 7;
    const int k0 = kh << 7;

    f32x4 acc[4][4];
    #pragma unroll
    for (int i = 0; i < 4; ++i)
        #pragma unroll
        for (int j = 0; j < 4; ++j)
            acc[i][j] = (f32x4){0.f, 0.f, 0.f, 0.f};

    for (int cc = 0; cc < 2; ++cc) {
        for (int r = 0; r < 3; ++r) {
            __syncthreads();   // previous compute done before overwrite
            {   // stage W slice: 3072 granules of 16 B, linear dest + inverse-swizzled source
                const unsigned short* wbase = Wp + ((size_t)((cc*3 + r)*3)*KOUT + k0)*64;
                #pragma unroll
                for (int it = 0; it < 12; ++it) {
                    const int t    = it*256 + tid;
                    const int phys = t << 4;
                    const int grow = phys >> 7;                      // s*128 + kk
                    const int cib  = (phys & 127) ^ ((grow & 7) << 4);
                    const int s    = grow >> 7;
                    const int kk   = grow & 127;
                    const unsigned short* src = wbase + ((size_t)(s*KOUT + kk))*64 + (cib >> 1);
                    g2lds16(src, smem + LDS_WS_OFF + phys);
                }
            }
            {   // stage X row slice: 1040 granules (rows p+r, all 130 w, 64 ci)
                const unsigned short* xbase = Xp + ((size_t)(n*HIN + (p + r))*WIN)*CIN + cc*64;
                #pragma unroll
                for (int it = 0; it < 5; ++it) {
                    const int t = it*256 + tid;
                    if (t < 1040) {
                        const int phys = t << 4;
                        const int w    = phys >> 7;
                        const int cib  = (phys & 127) ^ ((w & 7) << 4);
                        const unsigned short* src = xbase + (size_t)w*CIN + (cib >> 1);
                        g2lds16(src, smem + phys);
                    }
                }
            }
            asm volatile("s_waitcnt vmcnt(0)" ::: "memory");
            __syncthreads();

            #pragma unroll
            for (int s = 0; s < 3; ++s) {
                #pragma unroll
                for (int kq = 0; kq < 2; ++kq) {     // two K=32 sub-steps of the 64-ci chunk
                    const int cib = kq*64 + kg*16;   // byte offset of this lane's 8 ci
                    bf16x8 af[4], bx[4];
                    #pragma unroll
                    for (int mf = 0; mf < 4; ++mf) { // A = W fragments (rows = k_out)
                        const int row = wm*64 + mf*16 + l15;
                        af[mf] = *(const bf16x8*)(smem + LDS_WS_OFF + s*16384 + row*128
                                                  + (cib ^ ((row & 7) << 4)));
                    }
                    #pragma unroll
                    for (int nf = 0; nf < 4; ++nf) { // B = X fragments (cols = q), w = q + s
                        const int w = wn*64 + nf*16 + l15 + s;
                        bx[nf] = *(const bf16x8*)(smem + w*128 + (cib ^ ((w & 7) << 4)));
                    }
                    #pragma unroll
                    for (int mf = 0; mf < 4; ++mf)
                        #pragma unroll
                        for (int nf = 0; nf < 4; ++nf)
                            acc[mf][nf] = __builtin_amdgcn_mfma_f32_16x16x32_bf16(
                                af[mf], bx[nf], acc[mf][nf], 0, 0, 0);
                }
            }
        }
    }

    // epilogue: D col = q = lane&15, row = k_out = kg*4 + j  ->  coalesced 64-B segments
    #pragma unroll
    for (int mf = 0; mf < 4; ++mf) {
        const int kb = k0 + wm*64 + mf*16 + kg*4;
        const float4 bv = *(const float4*)(bias + kb);
        const float bj[4] = {bv.x, bv.y, bv.z, bv.w};
        #pragma unroll
        for (int nf = 0; nf < 4; ++nf) {
            const int q = wn*64 + nf*16 + l15;
            const size_t base = (((size_t)n*KOUT + kb)*POUT + p)*QOUT + q;
            #pragma unroll
            for (int j = 0; j < 4; ++j) {
                float y = (acc[mf][nf][j] + bj[j]) * 0.5f;
                out[base + (size_t)j*(POUT*QOUT)] = (y >= 0.f) ? y : y*NSLOPE;
            }
        }
    }
}

extern "C" void kernel_launch(void* const* d_in, const int* in_sizes, int n_in,
                              void* d_out, int out_size, void* d_ws, size_t ws_size,
                              hipStream_t stream) {
    const float* X = (const float*)d_in[0];
    const float* W = (const float*)d_in[1];
    const float* B = (const float*)d_in[2];
    float* out = (float*)d_out;
    unsigned short* Xp = (unsigned short*)d_ws;
    unsigned short* Wp = (unsigned short*)((char*)d_ws + XP_BYTES);

    k_conv_x   <<<NB*HIN, 256, 0, stream>>>(X, Xp);        // 4160 blocks
    k_conv_w   <<<(WP_ELEMS + 255)/256, 256, 0, stream>>>(W, Wp); // 1152 blocks
    k_conv_main<<<8192,    256, 0, stream>>>(Xp, Wp, B, out);
}